// Round 13
// baseline (266.790 us; speedup 1.0000x reference)
//
#include <hip/hip_runtime.h>

constexpr int IN_F  = 256;
constexpr int OUT_F = 512;
constexpr int BATCH = 2048;

// pack[(o,i)] = {p0,p1,p2,p3 | q1,q2,q3,w} : one aligned 32B record.
__global__ __launch_bounds__(256) void prep_pack8_kernel(
    const float* __restrict__ p, const float* __restrict__ q,
    const float* __restrict__ w, float4* __restrict__ pk, int n) {
    int t = blockIdx.x * 256 + threadIdx.x;
    if (t < n) {
        pk[2 * t]     = make_float4(p[4 * t], p[4 * t + 1], p[4 * t + 2], p[4 * t + 3]);
        pk[2 * t + 1] = make_float4(q[3 * t], q[3 * t + 1], q[3 * t + 2], w[t]);
    }
}

// x3[b,i] = RN(x^3) via f64, once per (b,i).
__global__ __launch_bounds__(256) void prep_x3_kernel(
    const float* __restrict__ x, float* __restrict__ x3, int n) {
    int t = blockIdx.x * 256 + threadIdx.x;
    if (t < n) {
        const double xd = (double)x[t];
        x3[t] = (float)(xd * xd * xd);   // RN(x^3) == powf(x,3)
    }
}

// R13: waves split BATCH, not i -- the four waves of a block s_load the
// IDENTICAL coefficient record sequence in the same order, so wave 1's K$
// miss (L2 ~250cy) becomes K$ hits (~30cy, MSHR-merged) for waves 2-4.
// Block = 4 waves x 64 lanes = 256 batches, o-tile = 2, full i-row per
// lane (no LDS, no reduction). Grid = 2048 blocks 1D = 8 blocks/CU = 32
// waves/CU (R6 occupancy preserved). Decomposition ot=bid&255, bb=bid>>8
// puts all 8 batch-blocks of an o-tile on ONE XCD (256 = 0 mod 8) -> the
// o-panel is L2-local. Per-chunk s_load footprint (8 records) is lighter
// than R6's proven 32. s_load->SGPR is the ONLY operand path that fits
// the register files: R7/R9/R12 (VGPR paths) and R10/R11 (wider tiles)
// all spilled to scratch and lost to R6's 108us.
//
// NUMERICS (verified R3-R12, absmax 768 vs threshold 5.7e5): per-element
// chain byte-identical -- x^2 = RN(x*x); x^3 = RN(x^3) via f64 table;
// S = fmaf chain ascending p starting from RN(c1*x); Q' = (1+S)+1e-6 as
// two separate adds; rcp division (relative-error-only); W-fma interleaved
// per element; i ascending. (i-sum is now one continuous chain instead of
// 4 wave-partials -- same terms, different grouping, error stays O(1e2).)
__global__ __launch_bounds__(256, 8) void kan4_kernel(
    const float*  __restrict__ x,
    const float4* __restrict__ PK,    // (O, I) 2x float4 records
    const float*  __restrict__ X3,    // (B, I) RN(x^3) table
    const float*  __restrict__ bias,  // (O)
    float* __restrict__ out)          // (B, O)
{
#pragma clang fp contract(off)       // protect the explicit add sequence
    const int lane = threadIdx.x & 63;
    const int wave = __builtin_amdgcn_readfirstlane(threadIdx.x >> 6);
    const int ot   = blockIdx.x & 255;          // o-tile -> XCD = ot & 7
    const int bb   = blockIdx.x >> 8;           // batch-block 0..7
    const int o0   = ot * 2;
    const int b    = bb * 256 + wave * 64 + lane;

    float acc[2] = {0.f, 0.f};
    const float* xrow  = x  + (size_t)b * IN_F;
    const float* x3row = X3 + (size_t)b * IN_F;

    for (int ic = 0; ic < IN_F; ic += 4) {
        const float4 xq  = *reinterpret_cast<const float4*>(xrow  + ic);
        const float4 x3q = *reinterpret_cast<const float4*>(x3row + ic);
        float x1[4]  = {xq.x, xq.y, xq.z, xq.w};
        float x3v[4] = {x3q.x, x3q.y, x3q.z, x3q.w};
        float x2[4];
#pragma unroll
        for (int j = 0; j < 4; ++j) x2[j] = x1[j] * x1[j];   // RN(x^2)

#pragma unroll
        for (int oo = 0; oo < 2; ++oo) {
            const int rowbase = (o0 + oo) * IN_F + ic;       // wave-uniform
#pragma unroll
            for (int j = 0; j < 4; ++j) {        // 32B records, R6 shape
                const float4 cp = PK[2 * (size_t)(rowbase + j)];
                const float4 cq = PK[2 * (size_t)(rowbase + j) + 1];
                // ---- S_Q : einsum fmaf chain, accum starts at 0 ----
                float t = cq.x * x1[j];          // == fma(q1,x1,0)
                t = fmaf(cq.y, x2[j], t);
                t = fmaf(cq.z, x3v[j], t);
                float Qv = 1.0f + t;             // Sterbenz-exact near pole
                float Qp = Qv + 1e-6f;
                // ---- S_P : same einsum chain ----
                float s = fmaf(cp.y, x1[j], cp.x);
                s = fmaf(cp.z, x2[j], s);
                s = fmaf(cp.w, x3v[j], s);
                const float r = __builtin_amdgcn_rcpf(Qp);
                acc[oo] = fmaf(s, r, acc[oo]);        // rational term
                acc[oo] = fmaf(cq.w, x1[j], acc[oo]); // fused base matmul
            }
        }
    }

    float2 res = make_float2(acc[0] + bias[o0], acc[1] + bias[o0 + 1]);
    *reinterpret_cast<float2*>(out + (size_t)b * OUT_F + o0) = res;
}

// R6 fallback (packed s_load / raw arrays) -- only used if ws too small.
template <int MODE>
__global__ __launch_bounds__(256, 8) void kan_kernel(
    const float*  __restrict__ x,
    const float4* __restrict__ Pc, const float* __restrict__ Qc,
    const float4* __restrict__ PK, const float* __restrict__ W,
    const float* __restrict__ bias, float* __restrict__ out)
{
#pragma clang fp contract(off)
    const int lane  = threadIdx.x & 63;
    const int wave  = __builtin_amdgcn_readfirstlane(threadIdx.x >> 6);
    const int b     = blockIdx.x * 64 + lane;
    const int o0    = blockIdx.y * 8;
    const int ibase = wave * 64;

    float acc[8] = {0.f, 0.f, 0.f, 0.f, 0.f, 0.f, 0.f, 0.f};
    const float* xrow = x + (size_t)b * IN_F + ibase;

    for (int ic = 0; ic < 64; ic += 4) {
        const float4 xq = *reinterpret_cast<const float4*>(xrow + ic);
        float x1[4] = {xq.x, xq.y, xq.z, xq.w};
        float x2[4], x3v[4];
#pragma unroll
        for (int j = 0; j < 4; ++j) {
            x2[j] = x1[j] * x1[j];
            const double xd = (double)x1[j];
            x3v[j] = (float)(xd * xd * xd);
        }
        const int rowi = ibase + ic;
#pragma unroll
        for (int oo = 0; oo < 8; ++oo) {
            const int rowbase = (o0 + oo) * IN_F + rowi;
#pragma unroll
            for (int j = 0; j < 4; ++j) {
                float p0, p1, p2, p3, q1, q2, q3, wv;
                if (MODE == 1) {
                    const float4 pa = PK[2 * (size_t)(rowbase + j)];
                    const float4 pb = PK[2 * (size_t)(rowbase + j) + 1];
                    p0 = pa.x; p1 = pa.y; p2 = pa.z; p3 = pa.w;
                    q1 = pb.x; q2 = pb.y; q3 = pb.z; wv = pb.w;
                } else {
                    const float4 pc = Pc[rowbase + j];
                    const float* qp = Qc + (size_t)(rowbase + j) * 3;
                    p0 = pc.x; p1 = pc.y; p2 = pc.z; p3 = pc.w;
                    q1 = qp[0]; q2 = qp[1]; q3 = qp[2];
                    wv = W[rowbase + j];
                }
                float t = q1 * x1[j];
                t = fmaf(q2, x2[j], t);
                t = fmaf(q3, x3v[j], t);
                float Qv = 1.0f + t;
                float Qp = Qv + 1e-6f;
                float s = fmaf(p1, x1[j], p0);
                s = fmaf(p2, x2[j], s);
                s = fmaf(p3, x3v[j], s);
                const float r = __builtin_amdgcn_rcpf(Qp);
                acc[oo] = fmaf(s, r, acc[oo]);
                acc[oo] = fmaf(wv, x1[j], acc[oo]);
            }
        }
    }

    __shared__ float red[4 * 64 * 9];
    {
        float* dst = &red[(wave * 64 + lane) * 9];
#pragma unroll
        for (int v = 0; v < 8; ++v) dst[v] = acc[v];
    }
    __syncthreads();
#pragma unroll
    for (int k = 0; k < 2; ++k) {
        const int idx = threadIdx.x + k * 256;
        const int bb = idx >> 3, o = idx & 7;
        const int e = bb * 9 + o;
        float s = red[e] + red[576 + e];
        s = s + red[1152 + e];
        s = s + red[1728 + e];
        s = s + bias[o0 + o];
        out[(size_t)(blockIdx.x * 64 + bb) * OUT_F + o0 + o] = s;
    }
}

extern "C" void kernel_launch(void* const* d_in, const int* in_sizes, int n_in,
                              void* d_out, int out_size, void* d_ws, size_t ws_size,
                              hipStream_t stream) {
    const float* x    = (const float*)d_in[0];
    const float* Pc   = (const float*)d_in[1];
    const float* Qc   = (const float*)d_in[2];
    const float* W    = (const float*)d_in[3];
    const float* bias = (const float*)d_in[4];
    float* out = (float*)d_out;

    const int n  = OUT_F * IN_F;          // 131072 (o,i) records
    const int nx = BATCH * IN_F;          // 524288 (b,i) x-powers
    const size_t pk_bytes = (size_t)n * 32;

    if (ws_size >= pk_bytes + (size_t)nx * sizeof(float)) {
        float4* pk = (float4*)d_ws;
        float*  x3 = (float*)((char*)d_ws + pk_bytes);
        prep_pack8_kernel<<<(n + 255) / 256, 256, 0, stream>>>(Pc, Qc, W, pk, n);
        prep_x3_kernel<<<(nx + 255) / 256, 256, 0, stream>>>(x, x3, nx);
        kan4_kernel<<<dim3(2048), 256, 0, stream>>>(x, pk, x3, bias, out);
    } else if (ws_size >= pk_bytes) {
        float4* pk = (float4*)d_ws;
        prep_pack8_kernel<<<(n + 255) / 256, 256, 0, stream>>>(Pc, Qc, W, pk, n);
        dim3 grid(BATCH / 64, OUT_F / 8);
        kan_kernel<1><<<grid, 256, 0, stream>>>(
            x, (const float4*)Pc, Qc, pk, W, bias, out);
    } else {
        dim3 grid(BATCH / 64, OUT_F / 8);
        kan_kernel<0><<<grid, 256, 0, stream>>>(
            x, (const float4*)Pc, Qc, nullptr, W, bias, out);
    }
}